// Round 4
// baseline (1261.992 us; speedup 1.0000x reference)
//
#include <hip/hip_runtime.h>
#include <math.h>

// Problem constants (fixed by the reference): B=256, S=2048, I=32, H=128, O=1
#define B_ 256
#define S_ 2048
#define I_ 32
#define H_ 128

// Barrier WITHOUT vmcnt(0) drain (HIP __syncthreads waits vmcnt(0) before
// s_barrier, stalling on in-flight global prefetch/stores every step).
// LDS visibility only needs lgkmcnt(0).
__device__ __forceinline__ void sync_lds() {
    asm volatile("" ::: "memory");
    asm volatile("s_waitcnt lgkmcnt(0)" ::: "memory");
    __builtin_amdgcn_s_barrier();
    asm volatile("" ::: "memory");
}

// tanh(z) = 1 - 2/(e^{2z}+1); exact limits at +-inf, abs err ~1e-7.
__device__ __forceinline__ float fast_tanh(float z) {
    float e = __expf(2.0f * z);
    return 1.0f - 2.0f / (e + 1.0f);
}

template <int CTRL>
__device__ __forceinline__ float dppf(float v) {
    return __int_as_float(__builtin_amdgcn_update_dpp(
        0, __float_as_int(v), CTRL, 0xF, 0xF, false));
}
// DPP controls: 0xB1 = quad_perm [1,0,3,2] (xor1), 0x4E = quad_perm [2,3,0,1]
// (xor2), 0x128 = row_ror:8 (xor8 within a 16-lane row).

// Full-wave (64-lane) sum, VALU-only; result valid in lane 63.
__device__ __forceinline__ float dpp_red_sum64(float v) {
    float t;
    t = __int_as_float(__builtin_amdgcn_update_dpp(0, __float_as_int(v), 0x111, 0xf, 0xf, false)); v += t;
    t = __int_as_float(__builtin_amdgcn_update_dpp(0, __float_as_int(v), 0x112, 0xf, 0xf, false)); v += t;
    t = __int_as_float(__builtin_amdgcn_update_dpp(0, __float_as_int(v), 0x114, 0xf, 0xf, false)); v += t;
    t = __int_as_float(__builtin_amdgcn_update_dpp(0, __float_as_int(v), 0x118, 0xf, 0xf, false)); v += t;
    t = __int_as_float(__builtin_amdgcn_update_dpp(0, __float_as_int(v), 0x142, 0xa, 0xf, false)); v += t;
    t = __int_as_float(__builtin_amdgcn_update_dpp(0, __float_as_int(v), 0x143, 0xc, 0xf, false)); v += t;
    return v;
}

#define MAC1(hval, idx)                              \
    a0 = fmaf(hval, WhR[(idx) * 4 + 0], a0);         \
    a1 = fmaf(hval, WhR[(idx) * 4 + 1], a1);         \
    a2 = fmaf(hval, WhR[(idx) * 4 + 2], a2);         \
    a3 = fmaf(hval, WhR[(idx) * 4 + 3], a3);
#define MAC4(hv, j)                                  \
    MAC1((hv).x, 4 * (j) + 0)                        \
    MAC1((hv).y, 4 * (j) + 1)                        \
    MAC1((hv).z, 4 * (j) + 2)                        \
    MAC1((hv).w, 4 * (j) + 3)

// One step of the recurrence. xsl = register slot holding x[b][s][i0..i0+16).
// All 256 lanes compute: lane owns 16 k x 4 h (64 FMAs, WhR[64]); partials
// reduced across the 8 k-group lanes {xor1, xor2 (quad_perm + cndmask h
// selection), xor8 (row_ror:8)} entirely on the VALU; lane ends with h =
// 4*hgrp + (l&3). Pair lane (l^8) is redundant -> splits xw = x.Wi (16 FMAs
// each, combined via one ror8 add). Score/proj for hn(s-1) run at step top,
// in the h0 ds_read latency shadow. ONE barrier per step.
#define STEP_BODY(s, xsl)                                                     \
  {                                                                           \
    if ((s) > 0) {                                                            \
      float wdv = wd_lds[((((s) - 1) & 7) << 7) + hf];                        \
      float pc = b3 ? 0.0f : hn_prev * waR;                                   \
      float qc = b3 ? 0.0f : hn_prev * wdv;                                   \
      pc = dpp_red_sum64(pc);                                                 \
      qc = dpp_red_sum64(qc);                                                 \
      if (l == 63) {                                                          \
        float2 v; v.x = pc; v.y = qc;                                         \
        pp_lds[((s) - 1) & 1][w] = v;                                         \
      }                                                                       \
    }                                                                         \
    if ((s) >= 2 && w == 3 && l == 0) {                                       \
      float4 c01 = *(const float4*)&pp_lds[(s) & 1][0];                       \
      float4 c23 = *(const float4*)&pp_lds[(s) & 1][2];                       \
      float2 o;                                                               \
      o.x = (c01.x + c01.z) + (c23.x + c23.z);                                \
      o.y = (c01.y + c01.w) + (c23.y + c23.w);                                \
      part[(((s) - 2) << 8) + b] = o;                                         \
    }                                                                         \
    const float4* hsrc = (const float4*)&h0_lds[(s) & 1][0];                  \
    float4 hv0 = hsrc[kg];                                                    \
    float4 hv1 = hsrc[kg + 8];                                                \
    float4 hv2 = hsrc[kg + 16];                                               \
    float4 hv3 = hsrc[kg + 24];                                               \
    float a0 = 0.f, a1 = 0.f, a2 = 0.f, a3 = 0.f;                             \
    MAC4(hv0, 0) MAC4(hv1, 1) MAC4(hv2, 2) MAC4(hv3, 3)                       \
    float d0 = dppf<0xB1>(a0), d1 = dppf<0xB1>(a1);                           \
    float d2 = dppf<0xB1>(a2), d3 = dppf<0xB1>(a3);                           \
    float v0 = (sel0 ? a1 : a0) + (sel0 ? d1 : d0);                           \
    float v1 = (sel0 ? a3 : a2) + (sel0 ? d3 : d2);                           \
    float e0 = dppf<0x4E>(v0), e1 = dppf<0x4E>(v1);                           \
    float uu = (sel1 ? v1 : v0) + (sel1 ? e1 : e0);                           \
    float tot = uu + dppf<0x128>(uu);                                         \
    float xwp = b3 ? 0.0f : biasR;                                            \
    xwp = fmaf(xsl[0].x, WiC[0],  xwp);                                       \
    xwp = fmaf(xsl[0].y, WiC[1],  xwp);                                       \
    xwp = fmaf(xsl[0].z, WiC[2],  xwp);                                       \
    xwp = fmaf(xsl[0].w, WiC[3],  xwp);                                       \
    xwp = fmaf(xsl[1].x, WiC[4],  xwp);                                       \
    xwp = fmaf(xsl[1].y, WiC[5],  xwp);                                       \
    xwp = fmaf(xsl[1].z, WiC[6],  xwp);                                       \
    xwp = fmaf(xsl[1].w, WiC[7],  xwp);                                       \
    xwp = fmaf(xsl[2].x, WiC[8],  xwp);                                       \
    xwp = fmaf(xsl[2].y, WiC[9],  xwp);                                       \
    xwp = fmaf(xsl[2].z, WiC[10], xwp);                                       \
    xwp = fmaf(xsl[2].w, WiC[11], xwp);                                       \
    xwp = fmaf(xsl[3].x, WiC[12], xwp);                                       \
    xwp = fmaf(xsl[3].y, WiC[13], xwp);                                       \
    xwp = fmaf(xsl[3].z, WiC[14], xwp);                                       \
    xwp = fmaf(xsl[3].w, WiC[15], xwp);                                       \
    float hn = tot + (xwp + dppf<0x128>(xwp));                                \
    {   /* refill slot with x(s+2); vmcnt-tracked, never drained by barrier */\
      int sx = (s) + 2; if (sx > S_ - 1) sx = S_ - 1;                         \
      const float4* xr = (const float4*)(xb_base + (size_t)sx * I_);          \
      xsl[0] = xr[0]; xsl[1] = xr[1]; xsl[2] = xr[2]; xsl[3] = xr[3];         \
    }                                                                         \
    float h0n;                                                                \
    if ((s) == 0)            { hstartR = hn; h0n = 0.0f; }                    \
    else if ((s) == S_ - 2)  { h0n = fast_tanh(hn + hstartR); }               \
    else if (rd == 1)        { h0n = fast_tanh(hn + h0R); }                   \
    else if (cnt == 0)       { h0n = fast_tanh(hn + htR); htR = hn; }         \
    else                     { h0n = fast_tanh(hn); }                         \
    h0R = h0n;                                                                \
    if (!b3) h0_lds[((s) + 1) & 1][hf] = h0n;                                 \
    hn_prev = hn;                                                             \
    cnt = (cnt + 1 == rd) ? 0 : cnt + 1;                                      \
    sync_lds();                                                               \
  }

__global__ __launch_bounds__(256, 1) void rnn_kernel(
    const float* __restrict__ x, const float* __restrict__ Wi,
    const float* __restrict__ bi, const float* __restrict__ Wh,
    const float* __restrict__ bh, const float* __restrict__ Wa,
    const float* __restrict__ Wd, const int* __restrict__ rdp,
    float2* __restrict__ part)
{
    const int b  = blockIdx.x;
    const int t  = threadIdx.x;
    const int w  = t >> 6;          // wave id
    const int l  = t & 63;
    const int b3 = (l >> 3) & 1;    // pair bit (redundant lane)
    const int kg = (l & 3) | (b3 << 2);                          // k-group 0..7
    const int hgrp = ((l >> 2) & 1) | (((l >> 4) & 3) << 1) | (w << 3); // 0..31
    const int hf = 4 * hgrp + (l & 3);                           // final h
    const bool sel0 = (l & 1);
    const bool sel1 = ((l >> 1) & 1);

    __shared__ __align__(16) float  h0_lds[2][H_];
    __shared__ __align__(16) float  wd_lds[8 * H_];
    __shared__ __align__(16) float2 pp_lds[2][4];

    const int rd = rdp[0];
    for (int j = t; j < 8 * H_; j += 256)
        wd_lds[j] = Wd[((j >> 7) << 15) + (b << 7) + (j & 127)];
    if (t < H_) h0_lds[0][t] = 0.0f;

    // Wh: lane's 16 k (k = 4kg + 32j + c) x 4 h (4*hgrp..+3)
    float WhR[64];
#pragma unroll
    for (int j = 0; j < 4; ++j)
#pragma unroll
        for (int c = 0; c < 4; ++c) {
            int k = 4 * kg + 32 * j + c;
            float4 wv = *(const float4*)(Wh + (size_t)k * H_ + 4 * hgrp);
            WhR[(4 * j + c) * 4 + 0] = wv.x;
            WhR[(4 * j + c) * 4 + 1] = wv.y;
            WhR[(4 * j + c) * 4 + 2] = wv.z;
            WhR[(4 * j + c) * 4 + 3] = wv.w;
        }
    // Wi: pair-split halves of the column for hf
    const int i0 = 16 * b3;
    float WiC[16];
#pragma unroll
    for (int i = 0; i < 16; ++i) WiC[i] = Wi[(i0 + i) * H_ + hf];
    const float waR   = Wa[hf];
    const float biasR = bi[hf] + bh[hf];

    // x register pipeline: two slots, slot[s&1] holds x(s) half-row
    const float* xb_base = x + (size_t)b * S_ * I_ + i0;
    float4 xb0[4], xb1[4];
#pragma unroll
    for (int r = 0; r < 4; ++r) xb0[r] = ((const float4*)(xb_base))[r];
#pragma unroll
    for (int r = 0; r < 4; ++r) xb1[r] = ((const float4*)(xb_base + I_))[r];

    sync_lds();

    float htR = 0.f, hstartR = 0.f, h0R = 0.f, hn_prev = 0.f;
    int cnt = 0;  // s % rd, incremental

    for (int s = 0; s < S_; s += 2) {
        STEP_BODY(s, xb0)
        STEP_BODY(s + 1, xb1)
    }

    // ---- epilogue: score for hn(S-1); combine S-2 then S-1 ----
    {
        float wdv = wd_lds[(((S_ - 1) & 7) << 7) + hf];
        float pc = b3 ? 0.0f : hn_prev * waR;
        float qc = b3 ? 0.0f : hn_prev * wdv;
        pc = dpp_red_sum64(pc);
        qc = dpp_red_sum64(qc);
        if (l == 63) {
            float2 v; v.x = pc; v.y = qc;
            pp_lds[(S_ - 1) & 1][w] = v;
        }
        if (w == 3 && l == 0) {   // pp[S_&1] holds s = S-2 (written in step S-1)
            float4 c01 = *(const float4*)&pp_lds[S_ & 1][0];
            float4 c23 = *(const float4*)&pp_lds[S_ & 1][2];
            float2 o;
            o.x = (c01.x + c01.z) + (c23.x + c23.z);
            o.y = (c01.y + c01.w) + (c23.y + c23.w);
            part[((S_ - 2) << 8) + b] = o;
        }
    }
    sync_lds();
    if (w == 3 && l == 0) {
        float4 c01 = *(const float4*)&pp_lds[(S_ - 1) & 1][0];
        float4 c23 = *(const float4*)&pp_lds[(S_ - 1) & 1][2];
        float2 o;
        o.x = (c01.x + c01.z) + (c23.x + c23.z);
        o.y = (c01.y + c01.w) + (c23.y + c23.w);
        part[((S_ - 1) << 8) + b] = o;
    }
}

// out[r] = bd + sum_{f in chunk r} softmax(score)_f * d_f, chunk = 2048 flat
// (s,b) pairs with s in [8r,8r+8). ba is softmax-invariant -> omitted.
__global__ __launch_bounds__(256) void attn_kernel(
    const float2* __restrict__ part, const float* __restrict__ bd,
    float* __restrict__ out)
{
    const int r = blockIdx.x;
    const int t = threadIdx.x;
    float sc[8], dv[8];
    float mx = -1e30f;
#pragma unroll
    for (int u = 0; u < 8; ++u) {
        int f = (r << 11) + (u << 8) + t;
        float2 a = part[f];
        sc[u] = a.x;
        dv[u] = a.y;
        mx = fmaxf(mx, sc[u]);
    }
    __shared__ float redm[4], redz[4], redw[4];
#pragma unroll
    for (int off = 32; off > 0; off >>= 1) mx = fmaxf(mx, __shfl_xor(mx, off, 64));
    if ((t & 63) == 0) redm[t >> 6] = mx;
    __syncthreads();
    mx = fmaxf(fmaxf(redm[0], redm[1]), fmaxf(redm[2], redm[3]));
    float z = 0.f, wv = 0.f;
#pragma unroll
    for (int u = 0; u < 8; ++u) {
        float e = __expf(sc[u] - mx);
        z += e;
        wv += e * dv[u];
    }
#pragma unroll
    for (int off = 32; off > 0; off >>= 1) {
        z += __shfl_xor(z, off, 64);
        wv += __shfl_xor(wv, off, 64);
    }
    if ((t & 63) == 0) { redz[t >> 6] = z; redw[t >> 6] = wv; }
    __syncthreads();
    if (t == 0) {
        float Z = redz[0] + redz[1] + redz[2] + redz[3];
        float W = redw[0] + redw[1] + redw[2] + redw[3];
        out[r] = bd[0] + W / Z;
    }
}

extern "C" void kernel_launch(void* const* d_in, const int* in_sizes, int n_in,
                              void* d_out, int out_size, void* d_ws, size_t ws_size,
                              hipStream_t stream) {
    const float* x  = (const float*)d_in[0];
    const float* Wi = (const float*)d_in[1];
    const float* bi = (const float*)d_in[2];
    const float* Wh = (const float*)d_in[3];
    const float* bh = (const float*)d_in[4];
    const float* Wa = (const float*)d_in[5];
    // d_in[6] = ba: constant shift inside each softmax chunk -> no effect.
    const float* Wd = (const float*)d_in[7];
    const float* bd = (const float*)d_in[8];
    const int*  rdp = (const int*)d_in[9];

    // Workspace: one (S*B) float2 array of combined {score, d} (4 MiB)
    float2* part = (float2*)d_ws;

    rnn_kernel<<<B_, 256, 0, stream>>>(x, Wi, bi, Wh, bh, Wa, Wd, rdp, part);
    attn_kernel<<<B_, 256, 0, stream>>>(part, bd, (float*)d_out);
}

// Round 5
// 1203.329 us; speedup vs baseline: 1.0488x; 1.0488x over previous
//
#include <hip/hip_runtime.h>
#include <math.h>

// Problem constants (fixed by the reference): B=256, S=2048, I=32, H=128, O=1
#define B_ 256
#define S_ 2048
#define I_ 32
#define H_ 128

// Barrier WITHOUT vmcnt(0) drain (HIP __syncthreads waits vmcnt(0) before
// s_barrier, stalling on in-flight global prefetch/stores every step).
// LDS visibility only needs lgkmcnt(0).
__device__ __forceinline__ void sync_lds() {
    asm volatile("" ::: "memory");
    asm volatile("s_waitcnt lgkmcnt(0)" ::: "memory");
    __builtin_amdgcn_s_barrier();
    asm volatile("" ::: "memory");
}

// tanh(z) = 1 - 2/(e^{2z}+1); exact limits at +-inf, abs err ~1e-7.
__device__ __forceinline__ float fast_tanh(float z) {
    float e = __expf(2.0f * z);
    return 1.0f - 2.0f / (e + 1.0f);
}

template <int CTRL>
__device__ __forceinline__ float dppf(float v) {
    return __int_as_float(__builtin_amdgcn_update_dpp(
        0, __float_as_int(v), CTRL, 0xF, 0xF, false));
}
// DPP controls: 0xB1 = quad_perm [1,0,3,2] (xor1), 0x4E = quad_perm [2,3,0,1]
// (xor2), 0x128 = row_ror:8 (xor8 within a 16-lane row).

// Full-wave (64-lane) sum, VALU-only; result valid in lane 63.
__device__ __forceinline__ float dpp_red_sum64(float v) {
    float t;
    t = __int_as_float(__builtin_amdgcn_update_dpp(0, __float_as_int(v), 0x111, 0xf, 0xf, false)); v += t;
    t = __int_as_float(__builtin_amdgcn_update_dpp(0, __float_as_int(v), 0x112, 0xf, 0xf, false)); v += t;
    t = __int_as_float(__builtin_amdgcn_update_dpp(0, __float_as_int(v), 0x114, 0xf, 0xf, false)); v += t;
    t = __int_as_float(__builtin_amdgcn_update_dpp(0, __float_as_int(v), 0x118, 0xf, 0xf, false)); v += t;
    t = __int_as_float(__builtin_amdgcn_update_dpp(0, __float_as_int(v), 0x142, 0xa, 0xf, false)); v += t;
    t = __int_as_float(__builtin_amdgcn_update_dpp(0, __float_as_int(v), 0x143, 0xc, 0xf, false)); v += t;
    return v;
}

#define MAC1(hval, idx)                              \
    a0 = fmaf(hval, WhR[(idx) * 4 + 0], a0);         \
    a1 = fmaf(hval, WhR[(idx) * 4 + 1], a1);         \
    a2 = fmaf(hval, WhR[(idx) * 4 + 2], a2);         \
    a3 = fmaf(hval, WhR[(idx) * 4 + 3], a3);
#define MAC4(hv, j)                                  \
    MAC1((hv).x, 4 * (j) + 0)                        \
    MAC1((hv).y, 4 * (j) + 1)                        \
    MAC1((hv).z, 4 * (j) + 2)                        \
    MAC1((hv).w, 4 * (j) + 3)

// One step. h0 ds_reads issue FIRST; the lagged score/proj DPP reductions run
// inside that LDS latency shadow; then the 64-FMA matvec, 8-lane DPP k-tree,
// pair-split xw = x.Wi, tanh branch, h0 publish. ONE barrier per step.
#define STEP_BODY(s, xsl)                                                     \
  {                                                                           \
    const float4* hsrc = (const float4*)&h0_lds[(s) & 1][0];                  \
    float4 hv0 = hsrc[kg];                                                    \
    float4 hv1 = hsrc[kg + 8];                                                \
    float4 hv2 = hsrc[kg + 16];                                               \
    float4 hv3 = hsrc[kg + 24];                                               \
    if ((s) > 0) {                                                            \
      float wdv = wd_lds[((((s) - 1) & 7) << 7) + hf];                        \
      float pc = b3 ? 0.0f : hn_prev * waR;                                   \
      float qc = b3 ? 0.0f : hn_prev * wdv;                                   \
      pc = dpp_red_sum64(pc);                                                 \
      qc = dpp_red_sum64(qc);                                                 \
      if (l == 63) {                                                          \
        float2 v; v.x = pc; v.y = qc;                                         \
        pp_lds[((s) - 1) & 1][w] = v;                                         \
      }                                                                       \
    }                                                                         \
    if ((s) >= 2 && w == 3 && l == 0) {                                       \
      float4 c01 = *(const float4*)&pp_lds[(s) & 1][0];                       \
      float4 c23 = *(const float4*)&pp_lds[(s) & 1][2];                       \
      float2 o;                                                               \
      o.x = (c01.x + c01.z) + (c23.x + c23.z);                                \
      o.y = (c01.y + c01.w) + (c23.y + c23.w);                                \
      part[(((s) - 2) << 8) + b] = o;                                         \
    }                                                                         \
    float a0 = 0.f, a1 = 0.f, a2 = 0.f, a3 = 0.f;                             \
    MAC4(hv0, 0) MAC4(hv1, 1) MAC4(hv2, 2) MAC4(hv3, 3)                       \
    float d0 = dppf<0xB1>(a0), d1 = dppf<0xB1>(a1);                           \
    float d2 = dppf<0xB1>(a2), d3 = dppf<0xB1>(a3);                           \
    float v0 = (sel0 ? a1 : a0) + (sel0 ? d1 : d0);                           \
    float v1 = (sel0 ? a3 : a2) + (sel0 ? d3 : d2);                           \
    float e0 = dppf<0x4E>(v0), e1 = dppf<0x4E>(v1);                           \
    float uu = (sel1 ? v1 : v0) + (sel1 ? e1 : e0);                           \
    float tot = uu + dppf<0x128>(uu);                                         \
    float xwp = b3 ? 0.0f : biasR;                                            \
    xwp = fmaf(xsl[0].x, WiC[0],  xwp);                                       \
    xwp = fmaf(xsl[0].y, WiC[1],  xwp);                                       \
    xwp = fmaf(xsl[0].z, WiC[2],  xwp);                                       \
    xwp = fmaf(xsl[0].w, WiC[3],  xwp);                                       \
    xwp = fmaf(xsl[1].x, WiC[4],  xwp);                                       \
    xwp = fmaf(xsl[1].y, WiC[5],  xwp);                                       \
    xwp = fmaf(xsl[1].z, WiC[6],  xwp);                                       \
    xwp = fmaf(xsl[1].w, WiC[7],  xwp);                                       \
    xwp = fmaf(xsl[2].x, WiC[8],  xwp);                                       \
    xwp = fmaf(xsl[2].y, WiC[9],  xwp);                                       \
    xwp = fmaf(xsl[2].z, WiC[10], xwp);                                       \
    xwp = fmaf(xsl[2].w, WiC[11], xwp);                                       \
    xwp = fmaf(xsl[3].x, WiC[12], xwp);                                       \
    xwp = fmaf(xsl[3].y, WiC[13], xwp);                                       \
    xwp = fmaf(xsl[3].z, WiC[14], xwp);                                       \
    xwp = fmaf(xsl[3].w, WiC[15], xwp);                                       \
    float hn = tot + (xwp + dppf<0x128>(xwp));                                \
    {   /* refill slot with x(s+2); vmcnt-tracked, never drained by barrier */\
      int sx = (s) + 2; if (sx > S_ - 1) sx = S_ - 1;                         \
      const float4* xr = (const float4*)(xb_base + (size_t)sx * I_);          \
      xsl[0] = xr[0]; xsl[1] = xr[1]; xsl[2] = xr[2]; xsl[3] = xr[3];         \
    }                                                                         \
    float h0n;                                                                \
    if ((s) == 0)            { hstartR = hn; h0n = 0.0f; }                    \
    else if ((s) == S_ - 2)  { h0n = fast_tanh(hn + hstartR); }               \
    else if (rd == 1)        { h0n = fast_tanh(hn + h0R); }                   \
    else if (cnt == 0)       { h0n = fast_tanh(hn + htR); htR = hn; }         \
    else                     { h0n = fast_tanh(hn); }                         \
    h0R = h0n;                                                                \
    if (!b3) h0_lds[((s) + 1) & 1][hf] = h0n;                                 \
    hn_prev = hn;                                                             \
    cnt = (cnt + 1 == rd) ? 0 : cnt + 1;                                      \
    sync_lds();                                                               \
  }

// waves_per_eu(1,1): exactly 1 wave/EU (our config is 4 waves on 4 SIMDs,
// 1 block/CU -- confirmed by steady ~12% occupancy). This hands the register
// allocator the full unified file so the ~150-VGPR working set (WhR[64] +
// xb[32] + WiC[16] + transients) stays in arch VGPRs instead of being
// shuttled through AGPRs/scratch every step (r3/r4 reported 136/76 VGPRs --
// far below static demand -- with the shuttle cost visible as +400 cyc/step
// of parasitic VALU).
__global__ __launch_bounds__(256)
__attribute__((amdgpu_waves_per_eu(1, 1)))
void rnn_kernel(
    const float* __restrict__ x, const float* __restrict__ Wi,
    const float* __restrict__ bi, const float* __restrict__ Wh,
    const float* __restrict__ bh, const float* __restrict__ Wa,
    const float* __restrict__ Wd, const int* __restrict__ rdp,
    float2* __restrict__ part)
{
    const int b  = blockIdx.x;
    const int t  = threadIdx.x;
    const int w  = t >> 6;          // wave id
    const int l  = t & 63;
    const int b3 = (l >> 3) & 1;    // pair bit
    const int kg = (l & 3) | (b3 << 2);                          // k-group 0..7
    const int hgrp = ((l >> 2) & 1) | (((l >> 4) & 3) << 1) | (w << 3); // 0..31
    const int hf = 4 * hgrp + (l & 3);                           // final h
    const bool sel0 = (l & 1);
    const bool sel1 = ((l >> 1) & 1);

    __shared__ __align__(16) float  h0_lds[2][H_];
    __shared__ __align__(16) float  wd_lds[8 * H_];
    __shared__ __align__(16) float2 pp_lds[2][4];

    const int rd = rdp[0];
    for (int j = t; j < 8 * H_; j += 256)
        wd_lds[j] = Wd[((j >> 7) << 15) + (b << 7) + (j & 127)];
    if (t < H_) h0_lds[0][t] = 0.0f;

    // Wh: lane's 16 k (k = 4kg + 32j + c) x 4 h (4*hgrp..+3)
    float WhR[64];
#pragma unroll
    for (int j = 0; j < 4; ++j)
#pragma unroll
        for (int c = 0; c < 4; ++c) {
            int k = 4 * kg + 32 * j + c;
            float4 wv = *(const float4*)(Wh + (size_t)k * H_ + 4 * hgrp);
            WhR[(4 * j + c) * 4 + 0] = wv.x;
            WhR[(4 * j + c) * 4 + 1] = wv.y;
            WhR[(4 * j + c) * 4 + 2] = wv.z;
            WhR[(4 * j + c) * 4 + 3] = wv.w;
        }
    // Wi: pair-split halves of the column for hf
    const int i0 = 16 * b3;
    float WiC[16];
#pragma unroll
    for (int i = 0; i < 16; ++i) WiC[i] = Wi[(i0 + i) * H_ + hf];
    const float waR   = Wa[hf];
    const float biasR = bi[hf] + bh[hf];

    // x register pipeline: two slots, slot[s&1] holds x(s) half-row
    const float* xb_base = x + (size_t)b * S_ * I_ + i0;
    float4 xb0[4], xb1[4];
#pragma unroll
    for (int r = 0; r < 4; ++r) xb0[r] = ((const float4*)(xb_base))[r];
#pragma unroll
    for (int r = 0; r < 4; ++r) xb1[r] = ((const float4*)(xb_base + I_))[r];

    sync_lds();

    float htR = 0.f, hstartR = 0.f, h0R = 0.f, hn_prev = 0.f;
    int cnt = 0;  // s % rd, incremental

    for (int s = 0; s < S_; s += 2) {
        STEP_BODY(s, xb0)
        STEP_BODY(s + 1, xb1)
    }

    // ---- epilogue: score for hn(S-1); combine S-2 then S-1 ----
    {
        float wdv = wd_lds[(((S_ - 1) & 7) << 7) + hf];
        float pc = b3 ? 0.0f : hn_prev * waR;
        float qc = b3 ? 0.0f : hn_prev * wdv;
        pc = dpp_red_sum64(pc);
        qc = dpp_red_sum64(qc);
        if (l == 63) {
            float2 v; v.x = pc; v.y = qc;
            pp_lds[(S_ - 1) & 1][w] = v;
        }
        if (w == 3 && l == 0) {   // pp[S_&1] holds s = S-2 (written in step S-1)
            float4 c01 = *(const float4*)&pp_lds[S_ & 1][0];
            float4 c23 = *(const float4*)&pp_lds[S_ & 1][2];
            float2 o;
            o.x = (c01.x + c01.z) + (c23.x + c23.z);
            o.y = (c01.y + c01.w) + (c23.y + c23.w);
            part[((S_ - 2) << 8) + b] = o;
        }
    }
    sync_lds();
    if (w == 3 && l == 0) {
        float4 c01 = *(const float4*)&pp_lds[(S_ - 1) & 1][0];
        float4 c23 = *(const float4*)&pp_lds[(S_ - 1) & 1][2];
        float2 o;
        o.x = (c01.x + c01.z) + (c23.x + c23.z);
        o.y = (c01.y + c01.w) + (c23.y + c23.w);
        part[((S_ - 1) << 8) + b] = o;
    }
}

// out[r] = bd + sum_{f in chunk r} softmax(score)_f * d_f, chunk = 2048 flat
// (s,b) pairs with s in [8r,8r+8). ba is softmax-invariant -> omitted.
__global__ __launch_bounds__(256) void attn_kernel(
    const float2* __restrict__ part, const float* __restrict__ bd,
    float* __restrict__ out)
{
    const int r = blockIdx.x;
    const int t = threadIdx.x;
    float sc[8], dv[8];
    float mx = -1e30f;
#pragma unroll
    for (int u = 0; u < 8; ++u) {
        int f = (r << 11) + (u << 8) + t;
        float2 a = part[f];
        sc[u] = a.x;
        dv[u] = a.y;
        mx = fmaxf(mx, sc[u]);
    }
    __shared__ float redm[4], redz[4], redw[4];
#pragma unroll
    for (int off = 32; off > 0; off >>= 1) mx = fmaxf(mx, __shfl_xor(mx, off, 64));
    if ((t & 63) == 0) redm[t >> 6] = mx;
    __syncthreads();
    mx = fmaxf(fmaxf(redm[0], redm[1]), fmaxf(redm[2], redm[3]));
    float z = 0.f, wv = 0.f;
#pragma unroll
    for (int u = 0; u < 8; ++u) {
        float e = __expf(sc[u] - mx);
        z += e;
        wv += e * dv[u];
    }
#pragma unroll
    for (int off = 32; off > 0; off >>= 1) {
        z += __shfl_xor(z, off, 64);
        wv += __shfl_xor(wv, off, 64);
    }
    if ((t & 63) == 0) { redz[t >> 6] = z; redw[t >> 6] = wv; }
    __syncthreads();
    if (t == 0) {
        float Z = redz[0] + redz[1] + redz[2] + redz[3];
        float W = redw[0] + redw[1] + redw[2] + redw[3];
        out[r] = bd[0] + W / Z;
    }
}

extern "C" void kernel_launch(void* const* d_in, const int* in_sizes, int n_in,
                              void* d_out, int out_size, void* d_ws, size_t ws_size,
                              hipStream_t stream) {
    const float* x  = (const float*)d_in[0];
    const float* Wi = (const float*)d_in[1];
    const float* bi = (const float*)d_in[2];
    const float* Wh = (const float*)d_in[3];
    const float* bh = (const float*)d_in[4];
    const float* Wa = (const float*)d_in[5];
    // d_in[6] = ba: constant shift inside each softmax chunk -> no effect.
    const float* Wd = (const float*)d_in[7];
    const float* bd = (const float*)d_in[8];
    const int*  rdp = (const int*)d_in[9];

    // Workspace: one (S*B) float2 array of combined {score, d} (4 MiB)
    float2* part = (float2*)d_ws;

    rnn_kernel<<<B_, 256, 0, stream>>>(x, Wi, bi, Wh, bh, Wa, Wd, rdp, part);
    attn_kernel<<<B_, 256, 0, stream>>>(part, bd, (float*)d_out);
}

// Round 6
// 1139.990 us; speedup vs baseline: 1.1070x; 1.0556x over previous
//
#include <hip/hip_runtime.h>
#include <math.h>

// Problem constants (fixed by the reference): B=256, S=2048, I=32, H=128, O=1
#define B_ 256
#define S_ 2048
#define I_ 32
#define H_ 128

// Barrier WITHOUT vmcnt(0) drain (HIP __syncthreads waits vmcnt(0) before
// s_barrier, stalling on in-flight global prefetch/stores every step).
// LDS visibility only needs lgkmcnt(0).
__device__ __forceinline__ void sync_lds() {
    asm volatile("" ::: "memory");
    asm volatile("s_waitcnt lgkmcnt(0)" ::: "memory");
    __builtin_amdgcn_s_barrier();
    asm volatile("" ::: "memory");
}

// tanh(z) = 1 - 2/(e^{2z}+1); exact limits at +-inf, abs err ~1e-7.
__device__ __forceinline__ float fast_tanh(float z) {
    float e = __expf(2.0f * z);
    return 1.0f - 2.0f / (e + 1.0f);
}

template <int CTRL>
__device__ __forceinline__ float dppf(float v) {
    return __int_as_float(__builtin_amdgcn_update_dpp(
        0, __float_as_int(v), CTRL, 0xF, 0xF, false));
}
// DPP controls: 0xB1 = quad_perm [1,0,3,2] (xor1), 0x4E = quad_perm [2,3,0,1]
// (xor2), 0x128 = row_ror:8 (exact xor8 within a 16-lane row).

// Full-wave (64-lane) sum, VALU-only; result valid in lane 63.
__device__ __forceinline__ float dpp_red_sum64(float v) {
    float t;
    t = __int_as_float(__builtin_amdgcn_update_dpp(0, __float_as_int(v), 0x111, 0xf, 0xf, false)); v += t;
    t = __int_as_float(__builtin_amdgcn_update_dpp(0, __float_as_int(v), 0x112, 0xf, 0xf, false)); v += t;
    t = __int_as_float(__builtin_amdgcn_update_dpp(0, __float_as_int(v), 0x114, 0xf, 0xf, false)); v += t;
    t = __int_as_float(__builtin_amdgcn_update_dpp(0, __float_as_int(v), 0x118, 0xf, 0xf, false)); v += t;
    t = __int_as_float(__builtin_amdgcn_update_dpp(0, __float_as_int(v), 0x142, 0xa, 0xf, false)); v += t;
    t = __int_as_float(__builtin_amdgcn_update_dpp(0, __float_as_int(v), 0x143, 0xc, 0xf, false)); v += t;
    return v;
}

#define MAC1(hval, idx)                              \
    a0 = fmaf(hval, WhR[(idx) * 2 + 0], a0);         \
    a1 = fmaf(hval, WhR[(idx) * 2 + 1], a1);
#define MAC4(hv, j)                                  \
    MAC1((hv).x, 4 * (j) + 0)                        \
    MAC1((hv).y, 4 * (j) + 1)                        \
    MAC1((hv).z, 4 * (j) + 2)                        \
    MAC1((hv).w, 4 * (j) + 3)

// One step. 8 waves per batch, wave w owns h in [16w,16w+16). Lane: 16k x 2h
// (32 FMA); k-tree over kg bits {xor1 w/ h-select, xor2, xor8} pure DPP.
// xw = x.Wi reduced over the duplicate-lane bits (xor2, xor8). Waves 4,6
// additionally do the lagged score/proj full-wave reductions from hn_lds.
// ONE barrier per step. XA/XB = x register slot (2 x float4, row s+2 loaded
// here; vmcnt-tracked across barriers, never drained by sync_lds).
#define STEP_BODY(s, XA, XB)                                                  \
  {                                                                           \
    const float4* hsrc = (const float4*)&h0_lds[(s) & 1][0];                  \
    float4 hv0 = hsrc[kg];                                                    \
    float4 hv1 = hsrc[kg + 8];                                                \
    float4 hv2 = hsrc[kg + 16];                                               \
    float4 hv3 = hsrc[kg + 24];                                               \
    if ((s) > 0) {                                                            \
      if (w == 4) {                                                           \
        float2 hp = *(const float2*)&hn_lds[((s) - 1) & 1][2 * l];            \
        float pv = fmaf(hp.x, waR0, hp.y * waR1);                             \
        pv = dpp_red_sum64(pv);                                               \
        if (l == 63) ((float*)part)[((((s) - 1) << 8) + b) * 2] = pv;         \
      } else if (w == 6) {                                                    \
        float2 hp = *(const float2*)&hn_lds[((s) - 1) & 1][2 * l];            \
        float2 wdp = *(const float2*)&wd_lds[((((s) - 1) & 7) << 7) + 2 * l]; \
        float qv = fmaf(hp.x, wdp.x, hp.y * wdp.y);                           \
        qv = dpp_red_sum64(qv);                                               \
        if (l == 63) ((float*)part)[((((s) - 1) << 8) + b) * 2 + 1] = qv;     \
      }                                                                       \
    }                                                                         \
    float a0 = 0.f, a1 = 0.f;                                                 \
    MAC4(hv0, 0) MAC4(hv1, 1) MAC4(hv2, 2) MAC4(hv3, 3)                       \
    float d0 = dppf<0xB1>(a0), d1 = dppf<0xB1>(a1);                           \
    float acc = (kb0b ? a1 : a0) + (kb0b ? d1 : d0);                          \
    acc += dppf<0x4E>(acc);                                                   \
    acc += dppf<0x128>(acc);                                                  \
    float xwp = biasR;                                                        \
    xwp = fmaf((XA).x, WiC[0], xwp);                                          \
    xwp = fmaf((XA).y, WiC[1], xwp);                                          \
    xwp = fmaf((XA).z, WiC[2], xwp);                                          \
    xwp = fmaf((XA).w, WiC[3], xwp);                                          \
    xwp = fmaf((XB).x, WiC[4], xwp);                                          \
    xwp = fmaf((XB).y, WiC[5], xwp);                                          \
    xwp = fmaf((XB).z, WiC[6], xwp);                                          \
    xwp = fmaf((XB).w, WiC[7], xwp);                                          \
    xwp += dppf<0x4E>(xwp);                                                   \
    xwp += dppf<0x128>(xwp);                                                  \
    float hn = acc + xwp;                                                     \
    {   /* refill slot with x row s+2 (clamped prefetch, in-bounds) */        \
      const float4* xr = (const float4*)xrow;                                 \
      (XA) = xr[0]; (XB) = xr[1];                                             \
      if ((s) <= S_ - 4) xrow += I_;                                          \
    }                                                                         \
    float h0n;                                                                \
    if ((s) == 0)            { hstartR = hn; h0n = 0.0f; }                    \
    else if ((s) == S_ - 2)  { h0n = fast_tanh(hn + hstartR); }               \
    else if (rd == 1)        { h0n = fast_tanh(hn + h0R); }                   \
    else if (cnt == 0)       { h0n = fast_tanh(hn + htR); htR = hn; }         \
    else                     { h0n = fast_tanh(hn); }                         \
    h0R = h0n;                                                                \
    if (wmask) {                                                              \
      h0_lds[((s) + 1) & 1][hf] = h0n;                                        \
      hn_lds[(s) & 1][hf] = hn;                                               \
    }                                                                         \
    cnt = (cnt + 1 == rd) ? 0 : cnt + 1;                                      \
    sync_lds();                                                               \
  }

// 512 threads = 8 waves per batch -> 2 waves/SIMD: independent waves hide
// each other's LDS/DPP/transcendental latency (r5 was 1 wave/SIMD, 48%
// VALUBusy = half the wall was exposed latency). waves_per_eu(2,2) caps the
// allocator at 256 VGPR/wave; static demand ~90 -> no spill.
__global__ __launch_bounds__(512)
__attribute__((amdgpu_waves_per_eu(2, 2)))
void rnn_kernel(
    const float* __restrict__ x, const float* __restrict__ Wi,
    const float* __restrict__ bi, const float* __restrict__ Wh,
    const float* __restrict__ bh, const float* __restrict__ Wa,
    const float* __restrict__ Wd, const int* __restrict__ rdp,
    float2* __restrict__ part)
{
    const int b = blockIdx.x;
    const int t = threadIdx.x;
    const int w = t >> 6;           // wave id 0..7
    const int l = t & 63;
    // k-group bits {0,1,3}; h-group bits {2,4,5}; duplicate-lane bits {1,3}
    const int  kg    = (l & 3) | (((l >> 3) & 1) << 2);              // 0..7
    const int  hg    = ((l >> 2) & 1) | (((l >> 4) & 1) << 1)
                     | (((l >> 5) & 1) << 2);                        // 0..7
    const int  hbase = 16 * w + 2 * hg;
    const int  hf    = hbase + (l & 1);     // this lane's final h
    const bool kb0b  = (l & 1);
    const bool wmask = ((l & 0xA) == 0);    // 16 writer lanes (distinct h)
    const int  i0x   = 8 * (((l >> 1) & 1) | (((l >> 3) & 1) << 1)); // 0,8,16,24

    __shared__ __align__(16) float h0_lds[2][H_];
    __shared__ __align__(16) float hn_lds[2][H_];
    __shared__ __align__(16) float wd_lds[8 * H_];

    const int rd = rdp[0];
    for (int j = t; j < 8 * H_; j += 512)
        wd_lds[j] = Wd[((j >> 7) << 15) + (b << 7) + (j & 127)];
    if (t < H_) h0_lds[0][t] = 0.0f;

    // Wh: lane's 16 k (k = 4kg + 32j + c) x 2 h (hbase, hbase+1)
    float WhR[32];
#pragma unroll
    for (int j = 0; j < 4; ++j)
#pragma unroll
        for (int c = 0; c < 4; ++c) {
            int k = 4 * kg + 32 * j + c;
            float2 wv = *(const float2*)(Wh + (size_t)k * H_ + hbase);
            WhR[(4 * j + c) * 2 + 0] = wv.x;
            WhR[(4 * j + c) * 2 + 1] = wv.y;
        }
    // Wi: this lane's i-slice (8 of 32) for its h
    float WiC[8];
#pragma unroll
    for (int i = 0; i < 8; ++i) WiC[i] = Wi[(size_t)(i0x + i) * H_ + hf];
    const float biasR = wmask ? (bi[hf] + bh[hf]) : 0.0f;  // added once per h
    const float waR0 = Wa[2 * l], waR1 = Wa[2 * l + 1];    // used by wave 4

    // x register pipeline: slot0 = row s (even s), slot1 = row s (odd s)
    const float* xrow = x + (size_t)b * S_ * I_ + i0x;
    float4 xA0 = ((const float4*)xrow)[0];
    float4 xB0 = ((const float4*)xrow)[1];
    float4 xA1 = ((const float4*)(xrow + I_))[0];
    float4 xB1 = ((const float4*)(xrow + I_))[1];
    xrow += 2 * I_;   // -> row 2 (next prefetch target)

    sync_lds();

    float htR = 0.f, hstartR = 0.f, h0R = 0.f;
    int cnt = 0;  // s % rd, incremental

    for (int s = 0; s < S_; s += 2) {
        STEP_BODY(s, xA0, xB0)
        STEP_BODY(s + 1, xA1, xB1)
    }

    // epilogue: score/proj for s = S-1 (lagged by one step)
    if (w == 4) {
        float2 hp = *(const float2*)&hn_lds[(S_ - 1) & 1][2 * l];
        float pv = fmaf(hp.x, waR0, hp.y * waR1);
        pv = dpp_red_sum64(pv);
        if (l == 63) ((float*)part)[(((S_ - 1) << 8) + b) * 2] = pv;
    } else if (w == 6) {
        float2 hp = *(const float2*)&hn_lds[(S_ - 1) & 1][2 * l];
        float2 wdp = *(const float2*)&wd_lds[(((S_ - 1) & 7) << 7) + 2 * l];
        float qv = fmaf(hp.x, wdp.x, hp.y * wdp.y);
        qv = dpp_red_sum64(qv);
        if (l == 63) ((float*)part)[(((S_ - 1) << 8) + b) * 2 + 1] = qv;
    }
}

// out[r] = bd + sum_{f in chunk r} softmax(score)_f * d_f, chunk = 2048 flat
// (s,b) pairs with s in [8r,8r+8). ba is softmax-invariant -> omitted.
__global__ __launch_bounds__(256) void attn_kernel(
    const float2* __restrict__ part, const float* __restrict__ bd,
    float* __restrict__ out)
{
    const int r = blockIdx.x;
    const int t = threadIdx.x;
    float sc[8], dv[8];
    float mx = -1e30f;
#pragma unroll
    for (int u = 0; u < 8; ++u) {
        int f = (r << 11) + (u << 8) + t;
        float2 a = part[f];
        sc[u] = a.x;
        dv[u] = a.y;
        mx = fmaxf(mx, sc[u]);
    }
    __shared__ float redm[4], redz[4], redw[4];
#pragma unroll
    for (int off = 32; off > 0; off >>= 1) mx = fmaxf(mx, __shfl_xor(mx, off, 64));
    if ((t & 63) == 0) redm[t >> 6] = mx;
    __syncthreads();
    mx = fmaxf(fmaxf(redm[0], redm[1]), fmaxf(redm[2], redm[3]));
    float z = 0.f, wv = 0.f;
#pragma unroll
    for (int u = 0; u < 8; ++u) {
        float e = __expf(sc[u] - mx);
        z += e;
        wv += e * dv[u];
    }
#pragma unroll
    for (int off = 32; off > 0; off >>= 1) {
        z += __shfl_xor(z, off, 64);
        wv += __shfl_xor(wv, off, 64);
    }
    if ((t & 63) == 0) { redz[t >> 6] = z; redw[t >> 6] = wv; }
    __syncthreads();
    if (t == 0) {
        float Z = redz[0] + redz[1] + redz[2] + redz[3];
        float W = redw[0] + redw[1] + redw[2] + redw[3];
        out[r] = bd[0] + W / Z;
    }
}

extern "C" void kernel_launch(void* const* d_in, const int* in_sizes, int n_in,
                              void* d_out, int out_size, void* d_ws, size_t ws_size,
                              hipStream_t stream) {
    const float* x  = (const float*)d_in[0];
    const float* Wi = (const float*)d_in[1];
    const float* bi = (const float*)d_in[2];
    const float* Wh = (const float*)d_in[3];
    const float* bh = (const float*)d_in[4];
    const float* Wa = (const float*)d_in[5];
    // d_in[6] = ba: constant shift inside each softmax chunk -> no effect.
    const float* Wd = (const float*)d_in[7];
    const float* bd = (const float*)d_in[8];
    const int*  rdp = (const int*)d_in[9];

    // Workspace: one (S*B) float2 array of combined {score, d} (4 MiB)
    float2* part = (float2*)d_ws;

    rnn_kernel<<<B_, 512, 0, stream>>>(x, Wi, bi, Wh, bh, Wa, Wd, rdp, part);
    attn_kernel<<<B_, 256, 0, stream>>>(part, bd, (float*)d_out);
}